// Round 1
// 631.232 us; speedup vs baseline: 1.0475x; 1.0475x over previous
//
#include <hip/hip_runtime.h>

namespace {

constexpr int TT = 1024;   // timesteps
constexpr int NB = 4096;   // batch
constexpr int H0 = 15, H1 = 10, H2 = 2;

// Pre-scales so activations use v_exp_f32 (exp2) directly:
// sigmoid(v) = 1/(1+exp2(-v*L2E)); tanh(u) = 2/(1+exp2(-u*2*L2E)) - 1.
constexpr float L2E  = 1.44269504088896340736f;
constexpr float L2E2 = 2.88539008177792681472f;

// Staging vector per sample (floats): x[0..4] pad[5..7] h0[8..22] pad[23]
// h1[24..33] pad[34..35] h2[36..37] pad[38..47].  Window starts (16B-aligned):
// L0 -> 0 (x+h0), L1 -> 8 (h0+h1), L2 -> 24 (h1+h2). Window = 28 floats.
constexpr int SSTRIDE = 48;

typedef float v2f __attribute__((ext_vector_type(2)));
typedef float v4f __attribute__((ext_vector_type(4)));

__device__ __forceinline__ float frcp(float v)  { return __builtin_amdgcn_rcpf(v); }
__device__ __forceinline__ float fexp2(float v) { return __builtin_amdgcn_exp2f(v); }
__device__ __forceinline__ float sigm_p(float v) { return frcp(1.0f + fexp2(-v)); }
__device__ __forceinline__ float tanh_p(float u) {
  return __builtin_fmaf(2.0f, frcp(1.0f + fexp2(-u)), -1.0f);
}

// Guaranteed packed FMA: d = a*b + c on both halves (v_pk_fma_f32).
__device__ __forceinline__ v2f pk_fma(v2f a, v2f b, v2f c) {
  v2f d;
  asm("v_pk_fma_f32 %0, %1, %2, %3" : "=v"(d) : "v"(a), "v"(b), "v"(c));
  return d;
}

}  // namespace

// Grid: 2048 blocks x 64 threads = 2 waves/SIMD. Wave = 2 samples x 32 lanes.
// Per sample: lanes 0-14 = L0 units, 15-24 = L1 units, 25-26 = L2 units,
// 27-31 = x-loaders. Uniform code: every lane reads a 28-float window of
// [x|h0|h1|h2] staging and does 4 zero-padded dots as 56 v_pk_fma_f32.
// Layers skewed (iter i: L0(i), L1(i-1), L2(i-2)) -> one publish/iteration.
// Single-wave block: no __syncthreads (wave-lockstep + in-order DS pipe);
// wave_barrier pins compiler ordering.
//
// x-prefetch pipeline (this revision): x has ZERO reuse -> every load is a
// ~900-cyc HBM-latency miss. The old code issued the prefetch and consumed
// its register in the SAME iteration (s_waitcnt vmcnt(0) per iter, ~600 cyc
// exposed stall). Now: registers xw/xn/xm hold x(i+1..i+3) and TWO loads
// stay in flight (xldA/xldB, statically distinct via manual unroll-2); the
// load issued at iter i is consumed at iter i+2 -> ~2 iterations (>1500 cyc)
// of slack -> the waitcnt never stalls.
extern "C" __global__ __launch_bounds__(64, 2) void gru3_fused(
    const float* __restrict__ x,
    const float* __restrict__ w_ih0, const float* __restrict__ w_hh0,
    const float* __restrict__ b_ih0, const float* __restrict__ b_hh0,
    const float* __restrict__ w_ih1, const float* __restrict__ w_hh1,
    const float* __restrict__ b_ih1, const float* __restrict__ b_hh1,
    const float* __restrict__ w_ih2, const float* __restrict__ w_hh2,
    const float* __restrict__ b_ih2, const float* __restrict__ b_hh2,
    float* __restrict__ out) {
  // 2 samples * 48 + tail pad so L2's window over-read stays in-buffer.
  __shared__ __attribute__((aligned(16))) float stage[112];

  const int tid  = threadIdx.x;
  const int lane = tid & 31;
  const int smp  = tid >> 5;
  const int b    = blockIdx.x * 2 + smp;
  const int sbase = smp * SSTRIDE;

  int cls, u;
  if (lane < 15)      { cls = 0; u = lane; }
  else if (lane < 25) { cls = 1; u = lane - 15; }
  else if (lane < 27) { cls = 2; u = lane - 25; }
  else                { cls = 3; u = lane - 27; }   // x-loader

  const int  woff   = (cls == 0) ? 0 : (cls == 1) ? 8 : (cls == 2) ? 24 : 0;
  const int  wpos   = (cls == 0) ? 8 + u : (cls == 1) ? 24 + u
                    : (cls == 2) ? 36 + u : u;
  const int  istart = cls;            // suppress h-update until layer's first step
  const bool is_x   = (cls == 3);
  const bool is_o   = (cls == 2);
  const int  xj     = is_x ? u : 0;   // in-bounds x column for everyone

  // ---- per-lane padded weight vectors (zero outside class's inputs) ----
  float Wr[28], Wz[28], Wnx[28], Wnh[28];
#pragma unroll
  for (int j = 0; j < 28; ++j) { Wr[j] = 0.f; Wz[j] = 0.f; Wnx[j] = 0.f; Wnh[j] = 0.f; }
  float br = 0.f, bz = 0.f, bnx = 0.f, bnh = 0.f;

  if (cls == 0) {
#pragma unroll
    for (int j = 0; j < 5; ++j) {
      Wr [j] = w_ih0[(u         ) * 5 + j] * L2E;
      Wz [j] = w_ih0[(H0 + u    ) * 5 + j] * L2E;
      Wnx[j] = w_ih0[(2 * H0 + u) * 5 + j] * L2E2;
    }
#pragma unroll
    for (int k = 0; k < 15; ++k) {
      Wr [8 + k] = w_hh0[(u         ) * 15 + k] * L2E;
      Wz [8 + k] = w_hh0[(H0 + u    ) * 15 + k] * L2E;
      Wnh[8 + k] = w_hh0[(2 * H0 + u) * 15 + k] * L2E2;
    }
    br  = (b_ih0[u] + b_hh0[u]) * L2E;
    bz  = (b_ih0[H0 + u] + b_hh0[H0 + u]) * L2E;
    bnx = b_ih0[2 * H0 + u] * L2E2;
    bnh = b_hh0[2 * H0 + u] * L2E2;
  } else if (cls == 1) {
#pragma unroll
    for (int k = 0; k < 15; ++k) {
      Wr [k] = w_ih1[(u         ) * 15 + k] * L2E;
      Wz [k] = w_ih1[(H1 + u    ) * 15 + k] * L2E;
      Wnx[k] = w_ih1[(2 * H1 + u) * 15 + k] * L2E2;
    }
#pragma unroll
    for (int k = 0; k < 10; ++k) {
      Wr [16 + k] = w_hh1[(u         ) * 10 + k] * L2E;
      Wz [16 + k] = w_hh1[(H1 + u    ) * 10 + k] * L2E;
      Wnh[16 + k] = w_hh1[(2 * H1 + u) * 10 + k] * L2E2;
    }
    br  = (b_ih1[u] + b_hh1[u]) * L2E;
    bz  = (b_ih1[H1 + u] + b_hh1[H1 + u]) * L2E;
    bnx = b_ih1[2 * H1 + u] * L2E2;
    bnh = b_hh1[2 * H1 + u] * L2E2;
  } else if (cls == 2) {
#pragma unroll
    for (int k = 0; k < 10; ++k) {
      Wr [k] = w_ih2[(u         ) * 10 + k] * L2E;
      Wz [k] = w_ih2[(H2 + u    ) * 10 + k] * L2E;
      Wnx[k] = w_ih2[(2 * H2 + u) * 10 + k] * L2E2;
    }
#pragma unroll
    for (int k = 0; k < 2; ++k) {
      Wr [12 + k] = w_hh2[(u         ) * 2 + k] * L2E;
      Wz [12 + k] = w_hh2[(H2 + u    ) * 2 + k] * L2E;
      Wnh[12 + k] = w_hh2[(2 * H2 + u) * 2 + k] * L2E2;
    }
    br  = (b_ih2[u] + b_hh2[u]) * L2E;
    bz  = (b_ih2[H2 + u] + b_hh2[H2 + u]) * L2E;
    bnx = b_ih2[2 * H2 + u] * L2E2;
    bnh = b_hh2[2 * H2 + u] * L2E2;
  }

  // pack to float2 for v_pk_fma_f32
  v2f Wr2[14], Wz2[14], Wnx2[14], Wnh2[14];
#pragma unroll
  for (int j = 0; j < 14; ++j) {
    Wr2 [j] = (v2f){Wr [2 * j], Wr [2 * j + 1]};
    Wz2 [j] = (v2f){Wz [2 * j], Wz [2 * j + 1]};
    Wnx2[j] = (v2f){Wnx[2 * j], Wnx[2 * j + 1]};
    Wnh2[j] = (v2f){Wnh[2 * j], Wnh[2 * j + 1]};
  }

  // ---- init staging (zeros = h(-1) states + pads), publish x(0) ----
  for (int j = tid; j < 112; j += 64) stage[j] = 0.0f;

  // x pipeline registers: at top of iter i, xw=x(i+1), xn=x(i+2), xm=x(i+3);
  // xldA/xldB hold in-flight loads of x(i+4), x(i+5) (consumed 2 iters after
  // issue). Prologue fills from rows 0..5 (TT=1024, all in-bounds).
  float xw, xn, xm, xldA, xldB;
  const size_t xstep = (size_t)NB * 5;
  {
    const size_t base = (size_t)b * 5 + xj;
    const float x0 = x[base];                 // t=0
    xw   = x[1 * xstep + base];               // t=1
    xn   = x[2 * xstep + base];               // t=2
    xm   = x[3 * xstep + base];               // t=3
    xldA = x[4 * xstep + base];               // t=4 (consumed at iter 0)
    xldB = x[5 * xstep + base];               // t=5 (consumed at iter 1)
    if (is_x) stage[sbase + u] = x0;
  }
  __builtin_amdgcn_wave_barrier();

  float h = 0.0f;
  const v4f* wloc = (const v4f*)&stage[sbase + woff];
  float* pub = &stage[sbase + wpos];

  // Strength-reduced pointers: x prefetch (row min(i+6, TT-1)) and out store.
  const float* xp = x + (size_t)6 * xstep + (size_t)b * 5 + xj;
  float* op = out + (size_t)b * H2 + (is_o ? u : 0);  // t = i-2 target
  const size_t ostep = (size_t)NB * H2;

#define GRU_DOT2(J, QH)               \
    aR  = pk_fma(Wr2 [J], (QH), aR);  \
    aZ  = pk_fma(Wz2 [J], (QH), aZ);  \
    aNx = pk_fma(Wnx2[J], (QH), aNx); \
    aNh = pk_fma(Wnh2[J], (QH), aNh);

// One skewed-pipeline GRU step. XR = the in-flight x-load register that is
// consumed this iteration (issued 2 iterations ago) and re-issued for row
// min(I+6, TT-1). Consuming a 2-iteration-old load means the implicit
// s_waitcnt targets an already-complete load -> no exposed HBM latency.
#define GRU_BODY(I, XR)                                                   \
  {                                                                       \
    const v4f q0 = wloc[0], q1 = wloc[1], q2 = wloc[2], q3 = wloc[3];     \
    const v4f q4 = wloc[4], q5 = wloc[5], q6 = wloc[6];                   \
    v2f aR  = (v2f){br,  0.f};                                            \
    v2f aZ  = (v2f){bz,  0.f};                                            \
    v2f aNx = (v2f){bnx, 0.f};                                            \
    v2f aNh = (v2f){bnh, 0.f};                                            \
    GRU_DOT2(0,  q0.lo)                                                   \
    GRU_DOT2(1,  q0.hi)                                                   \
    GRU_DOT2(2,  q1.lo)                                                   \
    GRU_DOT2(3,  q1.hi)                                                   \
    GRU_DOT2(4,  q2.lo)                                                   \
    GRU_DOT2(5,  q2.hi)                                                   \
    GRU_DOT2(6,  q3.lo)                                                   \
    GRU_DOT2(7,  q3.hi)                                                   \
    GRU_DOT2(8,  q4.lo)                                                   \
    GRU_DOT2(9,  q4.hi)                                                   \
    GRU_DOT2(10, q5.lo)                                                   \
    GRU_DOT2(11, q5.hi)                                                   \
    GRU_DOT2(12, q6.lo)                                                   \
    GRU_DOT2(13, q6.hi)                                                   \
    const float r = sigm_p(aR.x + aR.y);                                  \
    const float z = sigm_p(aZ.x + aZ.y);                                  \
    const float n = tanh_p((aNx.x + aNx.y) + r * (aNh.x + aNh.y));        \
    const float hnew = n + z * (h - n);                                   \
    h = ((I) >= istart) ? hnew : h;  /* junk-suppress before first step */ \
    *pub = is_x ? xw : h;            /* publish h (units) or x(I+1) */     \
    if ((I) >= 2) {                  /* uniform branch */                  \
      if (is_o) *op = h;             /* t = I-2, exec-masked */            \
      op += ostep;                                                        \
    }                                                                     \
    xw = xn; xn = xm; xm = XR;       /* waits on 2-iter-old load only */   \
    XR = *xp;                        /* issue x(min(I+6,TT-1)), no wait */ \
    if ((I) + 7 < TT) xp += xstep;   /* uniform scalar condition */        \
    __builtin_amdgcn_wave_barrier(); /* next reads after publishes */      \
  }

  // 1026 iterations total (even) -> 513 unroll-2 pairs; xldA/xldB alternate
  // so the two in-flight loads live in statically distinct registers.
#pragma unroll 1
  for (int i = 0; i <= TT + 1; i += 2) {
    GRU_BODY(i,     xldA)
    GRU_BODY(i + 1, xldB)
  }

#undef GRU_BODY
#undef GRU_DOT2
}

extern "C" void kernel_launch(void* const* d_in, const int* in_sizes, int n_in,
                              void* d_out, int out_size, void* d_ws, size_t ws_size,
                              hipStream_t stream) {
  (void)in_sizes; (void)n_in; (void)d_ws; (void)ws_size; (void)out_size;
  const float* x     = (const float*)d_in[0];
  const float* w_ih0 = (const float*)d_in[1];
  const float* w_hh0 = (const float*)d_in[2];
  const float* b_ih0 = (const float*)d_in[3];
  const float* b_hh0 = (const float*)d_in[4];
  const float* w_ih1 = (const float*)d_in[5];
  const float* w_hh1 = (const float*)d_in[6];
  const float* b_ih1 = (const float*)d_in[7];
  const float* b_hh1 = (const float*)d_in[8];
  const float* w_ih2 = (const float*)d_in[9];
  const float* w_hh2 = (const float*)d_in[10];
  const float* b_ih2 = (const float*)d_in[11];
  const float* b_hh2 = (const float*)d_in[12];
  float* out = (float*)d_out;

  gru3_fused<<<NB / 2, 64, 0, stream>>>(
      x, w_ih0, w_hh0, b_ih0, b_hh0,
      w_ih1, w_hh1, b_ih1, b_hh1,
      w_ih2, w_hh2, b_ih2, b_hh2, out);
}